// Round 12
// baseline (373.554 us; speedup 1.0000x reference)
//
#include <hip/hip_runtime.h>
#include <hip/hip_fp16.h>

typedef _Float16 f16;
typedef __attribute__((ext_vector_type(8))) _Float16 f16x8;
typedef __attribute__((ext_vector_type(4))) _Float16 f16x4;
typedef __attribute__((ext_vector_type(4))) float f32x4;

#define BM 128
#define BN 128
#define BK 64

__device__ __forceinline__ void gll16(const void* src, void* dst) {
  __builtin_amdgcn_global_load_lds((const __attribute__((address_space(1))) void*)src,
                                   (__attribute__((address_space(3))) void*)dst,
                                   16, 0, 0);
}

// C[m,n] = sum_k A[m,k] * B[n,k]  ("BT" form). m97-replica structure (R8, proven):
// 128x128 tile, BK=64, single-buffered 32 KiB LDS, 256 thr (4 waves, 64x64/wave),
// 2 barriers/K-tile; vmcnt-drain covered by 3 blocks/CU cross-block overlap (m114;
// measured hard cap — (256,4)/(256,6) don't raise it, R10/R11).
// R12: per-operand CVT flags — CVTA/CVTB=1 stages a fp32 operand via
// load(2x float4)->v_cvt->ds_write_b128 IN-LOOP (same LDS layout+swizzle; the
// loop-end __syncthreads' lgkmcnt drain publishes it). R6's failure mode was this
// pattern at 1 block/CU lockstep; at 3 blocks/CU the same cross-block overlap that
// covers the gll drain covers the stage wait.
// Swizzle: linear slot s of row r holds global slot s^(r&7) (0 conflicts measured).
// MODE 0: C fp16   MODE 1: P=exp(acc*scale+mask) fp16 + row-sum partials (32/row)
// MODE 2: C fp32 = acc / lvec[z*M+row]
template<int MODE, int CVTA, int CVTB>
__global__ __launch_bounds__(256, 3)
void gemm_bt(const void* __restrict__ Aall, const void* __restrict__ Ball,
             void* __restrict__ Call,
             int M, int N, int K, int lda, int ldb, int ldc,
             long strideA, long strideB, long strideC,
             const float* __restrict__ maskAll, long strideMask,
             float* __restrict__ lvec, float scale)
{
  __shared__ __align__(16) f16 smA[BM * BK];   // 16 KB
  __shared__ __align__(16) f16 smB[BN * BK];   // 16 KB  -> 32 KiB total

  // T1: bijective XCD-aware remap (all grids have nwg % 8 == 0)
  unsigned gx = gridDim.x, gy = gridDim.y;
  unsigned id = (blockIdx.z * gy + blockIdx.y) * gx + blockIdx.x;
  unsigned nwg = gx * gy * gridDim.z;
  unsigned swz = (id & 7) * (nwg >> 3) + (id >> 3);
  unsigned bx = swz % gx, rem = swz / gx;
  unsigned by = rem % gy, bz = rem / gy;

  const int z = bz;

  const int tid  = threadIdx.x;
  const int wid  = tid >> 6;
  const int lane = tid & 63;
  const int wm = wid >> 1;        // 0..1 -> 64 rows of C
  const int wn = wid & 1;         // 0..1 -> 64 cols of C
  const int lr = lane & 15;
  const int g  = lane >> 4;       // k-slot 0..3 (8 f16 each)

  const long brow = (long)by * BM;
  const long bcol = (long)bx * BN;
  const int  nt   = K / BK;

  f32x4 acc[4][4] = {};

  // stage one 128x64 tile (as f16 in LDS; 1024 chunks of 16B; 4 chunks/thread).
  // chunk c: row=c>>3, linear slot=c&7, global slot=(c&7)^(row&7).
  auto stA = [&](int t) {
    #pragma unroll
    for (int i = 0; i < 4; ++i) {
      int c  = i * 256 + tid;
      int r  = c >> 3;
      int sl = (c & 7) ^ (r & 7);
      long off = (brow + r) * (long)lda + t * BK + sl * 8;
      if constexpr (CVTA) {
        const float* s = (const float*)Aall + (long)z * strideA + off;
        float4 lo = *(const float4*)s, hi = *(const float4*)(s + 4);
        f16x8 o;
        o[0] = (f16)lo.x; o[1] = (f16)lo.y; o[2] = (f16)lo.z; o[3] = (f16)lo.w;
        o[4] = (f16)hi.x; o[5] = (f16)hi.y; o[6] = (f16)hi.z; o[7] = (f16)hi.w;
        *(f16x8*)(&smA[c * 8]) = o;
      } else {
        gll16((const f16*)Aall + (long)z * strideA + off, &smA[c * 8]);
      }
    }
  };
  auto stB = [&](int t) {
    #pragma unroll
    for (int i = 0; i < 4; ++i) {
      int c  = i * 256 + tid;
      int r  = c >> 3;
      int sl = (c & 7) ^ (r & 7);
      long off = (bcol + r) * (long)ldb + t * BK + sl * 8;
      if constexpr (CVTB) {
        const float* s = (const float*)Ball + (long)z * strideB + off;
        float4 lo = *(const float4*)s, hi = *(const float4*)(s + 4);
        f16x8 o;
        o[0] = (f16)lo.x; o[1] = (f16)lo.y; o[2] = (f16)lo.z; o[3] = (f16)lo.w;
        o[4] = (f16)hi.x; o[5] = (f16)hi.y; o[6] = (f16)hi.z; o[7] = (f16)hi.w;
        *(f16x8*)(&smB[c * 8]) = o;
      } else {
        gll16((const f16*)Ball + (long)z * strideB + off, &smB[c * 8]);
      }
    }
  };

  for (int t = 0; t < nt; ++t) {
    stA(t); stB(t);
    __syncthreads();                       // drains vmcnt AND lgkmcnt before barrier
    f16x8 af[8], bf[8];
    #pragma unroll
    for (int fm = 0; fm < 4; ++fm)
      #pragma unroll
      for (int ks = 0; ks < 2; ++ks) {
        int r = wm * 64 + fm * 16 + lr;
        af[fm * 2 + ks] = *(const f16x8*)(smA + r * BK + ((ks * 4 + g) ^ (r & 7)) * 8);
      }
    #pragma unroll
    for (int fn = 0; fn < 4; ++fn)
      #pragma unroll
      for (int ks = 0; ks < 2; ++ks) {
        int r = wn * 64 + fn * 16 + lr;
        bf[fn * 2 + ks] = *(const f16x8*)(smB + r * BK + ((ks * 4 + g) ^ (r & 7)) * 8);
      }
    #pragma unroll
    for (int fm = 0; fm < 4; ++fm)
      #pragma unroll
      for (int fn = 0; fn < 4; ++fn)
        #pragma unroll
        for (int ks = 0; ks < 2; ++ks)
          acc[fm][fn] = __builtin_amdgcn_mfma_f32_16x16x32_f16(
              af[fm * 2 + ks], bf[fn * 2 + ks], acc[fm][fn], 0, 0, 0);
    __syncthreads();                       // all reads done before next stage
  }

  // C/D layout (m89-verified): col = lane&15, row = (lane>>4)*4 + reg
  const int rb = (lane >> 4) * 4;

  if (MODE == 0) {
    f16* C = (f16*)Call + (long)z * strideC;
    #pragma unroll
    for (int m = 0; m < 4; ++m)
      #pragma unroll
      for (int j = 0; j < 4; ++j) {
        long grow = brow + wm * 64 + m * 16 + rb + j;
        #pragma unroll
        for (int n = 0; n < 4; ++n) {
          long gcol = bcol + wn * 64 + n * 16 + lr;
          C[grow * ldc + gcol] = (f16)acc[m][n][j];
        }
      }
  } else if (MODE == 1) {
    f16* C = (f16*)Call + (long)z * strideC;
    const float* mask = maskAll + (long)z * strideMask;
    #pragma unroll
    for (int m = 0; m < 4; ++m)
      #pragma unroll
      for (int j = 0; j < 4; ++j) {
        long grow = brow + wm * 64 + m * 16 + rb + j;
        float s = 0.f;
        #pragma unroll
        for (int n = 0; n < 4; ++n) {
          long gcol = bcol + wn * 64 + n * 16 + lr;
          float p = __expf(acc[m][n][j] * scale + mask[grow * ldc + gcol]);
          C[grow * ldc + gcol] = (f16)p;
          s += p;
        }
        s += __shfl_xor(s, 1);
        s += __shfl_xor(s, 2);
        s += __shfl_xor(s, 4);
        s += __shfl_xor(s, 8);
        if (lr == 0)
          lvec[((long)z * M + grow) * 32 + bx * 2 + wn] = s;
      }
  } else {
    float* C = (float*)Call + (long)z * strideC;
    #pragma unroll
    for (int m = 0; m < 4; ++m)
      #pragma unroll
      for (int j = 0; j < 4; ++j) {
        long grow = brow + wm * 64 + m * 16 + rb + j;
        float inv = 1.0f / lvec[(long)z * M + grow];
        #pragma unroll
        for (int n = 0; n < 4; ++n) {
          long gcol = bcol + wn * 64 + n * 16 + lr;
          C[grow * ldc + gcol] = acc[m][n][j] * inv;
        }
      }
  }
}

// grid-strided fp32->fp16 convert: k, Wv only (q/v fused into GEMM staging)
__global__ void cvt_all(const float* __restrict__ k, const float* __restrict__ Wv,
                        f16* __restrict__ kf, f16* __restrict__ Wvf)
{
  const long NQ4 = 4194304, NW4 = 262144;       // float4 counts
  const long total = NQ4 + NW4;
  for (long i = (long)blockIdx.x * blockDim.x + threadIdx.x; i < total;
       i += (long)gridDim.x * blockDim.x) {
    const float* src; f16* dst; long j = i;
    if (j < NQ4) { src = k;  dst = kf; }
    else         { src = Wv; dst = Wvf; j -= NQ4; }
    float4 vv = ((const float4*)src)[j];
    f16x4 o;
    o[0] = (f16)vv.x; o[1] = (f16)vv.y; o[2] = (f16)vv.z; o[3] = (f16)vv.w;
    ((f16x4*)dst)[j] = o;
  }
}

// 64x64-tile LDS transpose + fp32->fp16: WT[d][h] = (f16)W[h][d], for Wq and Wk.
__global__ void transW(const float* __restrict__ Wq, const float* __restrict__ Wk,
                       f16* __restrict__ WqT, f16* __restrict__ WkT)
{
  __shared__ f16 t[64][65];
  const float* W  = blockIdx.z ? Wk : Wq;
  f16*         WT = blockIdx.z ? WkT : WqT;
  const int h0 = blockIdx.y * 64, d0 = blockIdx.x * 64;
  const int tx = threadIdx.x & 15, ty = threadIdx.x >> 4;   // 16 x 16
  #pragma unroll
  for (int p = 0; p < 4; ++p) {
    int h = ty + p * 16;
    float4 vv = *(const float4*)(W + (long)(h0 + h) * 1024 + d0 + tx * 4);
    t[tx * 4 + 0][h] = (f16)vv.x;
    t[tx * 4 + 1][h] = (f16)vv.y;
    t[tx * 4 + 2][h] = (f16)vv.z;
    t[tx * 4 + 3][h] = (f16)vv.w;
  }
  __syncthreads();
  #pragma unroll
  for (int p = 0; p < 4; ++p) {
    int d = ty + p * 16;
    f16x4 o;
    o[0] = t[d][tx * 4 + 0];
    o[1] = t[d][tx * 4 + 1];
    o[2] = t[d][tx * 4 + 2];
    o[3] = t[d][tx * 4 + 3];
    *(f16x4*)(WT + (long)(d0 + d) * 1024 + h0 + tx * 4) = o;
  }
}

__global__ void reduce_l(const float* __restrict__ lpart, float* __restrict__ lsum, int n) {
  int i = blockIdx.x * blockDim.x + threadIdx.x;
  if (i < n) {
    float s = 0.f;
    #pragma unroll
    for (int j = 0; j < 32; ++j) s += lpart[(long)i * 32 + j];
    lsum[i] = s;
  }
}

extern "C" void kernel_launch(void* const* d_in, const int* in_sizes, int n_in,
                              void* d_out, int out_size, void* d_ws, size_t ws_size,
                              hipStream_t stream)
{
  const float* q    = (const float*)d_in[0];
  const float* k    = (const float*)d_in[1];
  const float* v    = (const float*)d_in[2];
  const float* mask = (const float*)d_in[3];
  const float* Wq   = (const float*)d_in[4];
  const float* Wk   = (const float*)d_in[5];
  const float* Wv   = (const float*)d_in[6];
  float* out = (float*)d_out;
  char*  ws  = (char*)d_ws;

  // workspace layout (bytes). Pm overwrites nothing live (qf/vf no longer exist).
  f16*   Pm    = (f16*)(ws + 0);           // 64 MB
  f16*   kf    = (f16*)(ws + 67108864);    // 32 MB   (raw k fp16, read by scores)
  f16*   Wvf   = (f16*)(ws + 100663296);   // 2 MB
  f16*   WqT   = (f16*)(ws + 102760448);   // 2 MB    WqT[d][h]
  f16*   WkT   = (f16*)(ws + 104857600);   // 2 MB    WkT[d][h]
  f16*   Gt    = (f16*)(ws + 106954752);   // 2 MB    Gt[d'][d] = sum_h Wk[h,d']Wq[h,d]
  f16*   qg    = (f16*)(ws + 109051904);   // 32 MB   qg[l,d'] = sum_d q[l,d] G[d,d']
  f16*   vpT   = (f16*)(ws + 142606336);   // 32 MB   (stored H x J, transposed)
  float* lpart = (float*)(ws + 176160768); // 2 MB
  float* lsum  = (float*)(ws + 178257920); // 64 KB

  const long L = 2048, J = 2048, D = 1024, H = 1024;

  // 1) converts: k,Wv fp32->fp16 ; Wq,Wk fp32->fp16 TRANSPOSED (q,v fused below)
  cvt_all<<<dim3(1024), dim3(256), 0, stream>>>(k, Wv, kf, Wvf);
  transW<<<dim3(16, 16, 2), dim3(256), 0, stream>>>(Wq, Wk, WqT, WkT);

  // 2) Gt[d',d] = sum_h WkT[d',h] * WqT[d,h]   M=N=K=1024 (tiny, 2.1 GF)
  gemm_bt<0, 0, 0><<<dim3(1024 / BN, 1024 / BM, 1), dim3(256), 0, stream>>>(
      WkT, WqT, Gt, 1024, 1024, 1024, 1024, 1024, 1024,
      0, 0, 0, nullptr, 0, nullptr, 0.f);

  // 3) qg[l,d'] = sum_d q[l,d] * Gt[d',d]   M=16384 N=1024 K=1024, A = RAW q fp32
  gemm_bt<0, 1, 0><<<dim3(1024 / BN, 16384 / BM, 1), dim3(256), 0, stream>>>(
      q, Gt, qg, 16384, 1024, 1024, 1024, 1024, 1024,
      0, 0, 0, nullptr, 0, nullptr, 0.f);

  // 4) vpT[b][h,j] = sum_d Wv[h,d] * v[b][j,d]   M=1024 N=2048 K=1024, B = RAW v fp32
  gemm_bt<0, 0, 1><<<dim3(2048 / BN, 1024 / BM, 8), dim3(256), 0, stream>>>(
      Wvf, v, vpT, 1024, 2048, 1024, 1024, 1024, 2048,
      0, J * D, H * J, nullptr, 0, nullptr, 0.f);

  // 5) P[b][l,j] = exp(qg.kf^T / 32 + mask), fp16, + row-sum partials
  //    (scores = qp.kp^T by associativity: qg = q.Wq^T.Wk, kf = raw k)
  gemm_bt<1, 0, 0><<<dim3(2048 / BN, 2048 / BM, 8), dim3(256), 0, stream>>>(
      qg, kf, Pm, 2048, 2048, 1024, 1024, 1024, 2048,
      L * D, J * D, L * J, mask, L * J, lpart, 0.03125f);

  reduce_l<<<dim3(16384 / 256), dim3(256), 0, stream>>>(lpart, lsum, 16384);

  // 6) out[b][l,h] = (sum_j P[l,j] * vpT[h,j]) / l[b,l]   M=2048 N=1024 K=2048
  gemm_bt<2, 0, 0><<<dim3(1024 / BN, 2048 / BM, 8), dim3(256), 0, stream>>>(
      Pm, vpT, out, 2048, 1024, 2048, 2048, 2048, 1024,
      L * J, H * J, L * H, nullptr, 0, lsum, 0.f);
}